// Round 10
// baseline (187.210 us; speedup 1.0000x reference)
//
#include <hip/hip_runtime.h>
#include <stdint.h>

#define Bn 256
#define Tn 50
#define Mn 20
#define En 128
#define G3 384
#define MT 64
#define LDA 132

__device__ __forceinline__ float sigmoidf(float x) {
    return 1.0f / (1.0f + __expf(-x));
}
__device__ __forceinline__ float tanh_safe(float a) {
    float ax = fabsf(a);
    float e2 = __expf(-2.0f * ax);
    return copysignf((1.0f - e2) / (1.0f + e2), a);
}

// ---------------------------------------------------------------------------
// Kernel 1: basket-mean gather -> ub [B*T][128]  (stored in d_out region)
// ---------------------------------------------------------------------------
__global__ __launch_bounds__(256) void gather_kernel(
    const int*   __restrict__ item_ids,
    const int*   __restrict__ basket_sizes,
    const float* __restrict__ emb,
    float* __restrict__ ub)
{
    const int bt   = blockIdx.x * 8 + (threadIdx.x >> 5);
    const int lane = threadIdx.x & 31;
    const int* ids = item_ids + (size_t)bt * Mn;
    float ax = 0.f, ay = 0.f, az = 0.f, aw = 0.f;
    #pragma unroll
    for (int m = 0; m < Mn; ++m) {
        const float4 v = *(const float4*)(emb + (size_t)ids[m] * En + lane * 4);
        ax += v.x; ay += v.y; az += v.z; aw += v.w;
    }
    const float inv = 1.0f / (float)basket_sizes[bt];
    *(float4*)(ub + (size_t)bt * En + lane * 4) =
        make_float4(ax * inv, ay * inv, az * inv, aw * inv);
}

// ---------------------------------------------------------------------------
// Kernel 2: xg = ub @ W_ih^T + b_ih.  1200 blocks (200 M x 6 N); 4x4 tile.
// ---------------------------------------------------------------------------
__global__ __launch_bounds__(256, 2) void gemm_kernel(
    const float* __restrict__ ub,
    const float* __restrict__ W_ih,
    const float* __restrict__ b_ih,
    float* __restrict__ xg)
{
    __shared__ float A[MT][LDA];
    __shared__ float Bt[64][LDA];

    const int tid  = threadIdx.x;
    const int mt   = blockIdx.x / 6;
    const int nc   = blockIdx.x % 6;
    const int row0 = mt * MT;
    const int col0 = nc * 64;

    {
        const int r = tid >> 2, seg = tid & 3;
        const float4* srcA = (const float4*)(ub + (size_t)(row0 + r) * En + seg * 32);
        const float4* srcB = (const float4*)(W_ih + (size_t)(col0 + r) * En + seg * 32);
        float4* dstA = (float4*)&A[r][seg * 32];
        float4* dstB = (float4*)&Bt[r][seg * 32];
        #pragma unroll
        for (int c = 0; c < 8; ++c) { dstA[c] = srcA[c]; dstB[c] = srcB[c]; }
    }
    __syncthreads();

    const int tx = tid & 15;
    const int ty = tid >> 4;

    float acc[4][4];
    #pragma unroll
    for (int i = 0; i < 4; ++i)
        #pragma unroll
        for (int u = 0; u < 4; ++u) acc[i][u] = 0.0f;

    #pragma unroll 4
    for (int k4 = 0; k4 < 32; ++k4) {
        const float4 av[4] = {
            *(const float4*)&A[ty +  0][k4*4], *(const float4*)&A[ty + 16][k4*4],
            *(const float4*)&A[ty + 32][k4*4], *(const float4*)&A[ty + 48][k4*4]};
        const float4 bv[4] = {
            *(const float4*)&Bt[tx +  0][k4*4], *(const float4*)&Bt[tx + 16][k4*4],
            *(const float4*)&Bt[tx + 32][k4*4], *(const float4*)&Bt[tx + 48][k4*4]};
        #pragma unroll
        for (int i = 0; i < 4; ++i)
            #pragma unroll
            for (int u = 0; u < 4; ++u) {
                acc[i][u] = fmaf(av[i].x, bv[u].x, acc[i][u]);
                acc[i][u] = fmaf(av[i].y, bv[u].y, acc[i][u]);
                acc[i][u] = fmaf(av[i].z, bv[u].z, acc[i][u]);
                acc[i][u] = fmaf(av[i].w, bv[u].w, acc[i][u]);
            }
    }

    float bias[4];
    #pragma unroll
    for (int u = 0; u < 4; ++u) bias[u] = b_ih[col0 + tx + 16*u];
    #pragma unroll
    for (int i = 0; i < 4; ++i) {
        const size_t rowoff = (size_t)(row0 + ty + 16*i) * G3;
        #pragma unroll
        for (int u = 0; u < 4; ++u)
            xg[rowoff + col0 + tx + 16*u] = acc[i][u] + bias[u];
    }
}

// ---------------------------------------------------------------------------
// Kernel 3: sequential GRU. 256 blocks x 1024 threads.
// Thread (j in [0,128), q in [0,8)) owns 48 W_hh floats, parked in AGPRs via
// v_accvgpr_write_b32 (gfx950 unified RF). Per step they come back through
// volatile v_accvgpr_read_b32 -> the allocator cannot sink the global loads
// (values live in AGPR class) and the per-step 196KB/block L2 stream dies.
// ---------------------------------------------------------------------------
#define PARKW(av, vv) asm volatile("v_accvgpr_write_b32 %0, %1" : "=a"(av) : "v"(vv))
#define GETW(vv, av)  asm volatile("v_accvgpr_read_b32 %0, %1" : "=v"(vv) : "a"(av))
#define W4DECL(p) float p##0, p##1, p##2, p##3
#define PARK4(p, v4) do { PARKW(p##0, (v4).x); PARKW(p##1, (v4).y); \
                          PARKW(p##2, (v4).z); PARKW(p##3, (v4).w); } while (0)
#define DOT4G(acc, p, hv) do { float t0, t1, t2, t3; \
    GETW(t0, p##0); GETW(t1, p##1); GETW(t2, p##2); GETW(t3, p##3); \
    acc = fmaf(t0, (hv).x, acc); acc = fmaf(t1, (hv).y, acc); \
    acc = fmaf(t2, (hv).z, acc); acc = fmaf(t3, (hv).w, acc); } while (0)

__global__ __launch_bounds__(1024)
__attribute__((amdgpu_waves_per_eu(4, 4)))
void gru_kernel(
    const int*   __restrict__ lengths,
    const float* __restrict__ W_hh,
    const float* __restrict__ b_hh,
    const float* __restrict__ h0,
    const float* __restrict__ xg,
    float* __restrict__ out_dyn,
    float* __restrict__ out_h)
{
    __shared__ float hs[En];
    __shared__ float red[8][3][En];   // [q][gate][j], 12 KB

    const int tid = threadIdx.x;
    const int b   = blockIdx.x;
    const int j   = tid & 127;
    const int q   = tid >> 7;         // [0,8), wave-uniform

    // gate g row g*128+j, cols [q*16, q*16+16): 12 float4 -> 48 AGPRs
    W4DECL(a00); W4DECL(a01); W4DECL(a02); W4DECL(a03);
    W4DECL(a10); W4DECL(a11); W4DECL(a12); W4DECL(a13);
    W4DECL(a20); W4DECL(a21); W4DECL(a22); W4DECL(a23);
    {
        const float4* p0 = (const float4*)(W_hh + (size_t)(0*En + j) * En + q * 16);
        const float4* p1 = (const float4*)(W_hh + (size_t)(1*En + j) * En + q * 16);
        const float4* p2 = (const float4*)(W_hh + (size_t)(2*En + j) * En + q * 16);
        float4 v;
        v = p0[0]; PARK4(a00, v); v = p0[1]; PARK4(a01, v);
        v = p0[2]; PARK4(a02, v); v = p0[3]; PARK4(a03, v);
        v = p1[0]; PARK4(a10, v); v = p1[1]; PARK4(a11, v);
        v = p1[2]; PARK4(a12, v); v = p1[3]; PARK4(a13, v);
        v = p2[0]; PARK4(a20, v); v = p2[1]; PARK4(a21, v);
        v = p2[2]; PARK4(a22, v); v = p2[3]; PARK4(a23, v);
    }

    const int len = lengths[b];
    const float* xgb = xg + (size_t)b * Tn * G3;
    float* outb = out_dyn + (size_t)b * Tn * En;

    float xr = 0.f, xz = 0.f, xn = 0.f, br = 0.f, bz = 0.f, bn = 0.f;
    if (tid < En) {
        hs[tid] = h0[(size_t)b * En + tid];
        br = b_hh[tid]; bz = b_hh[En + tid]; bn = b_hh[2*En + tid];
        xr = xgb[tid];  xz = xgb[En + tid]; xn = xgb[2*En + tid];
    }
    __syncthreads();

    for (int t = 0; t < len; ++t) {
        // phase A: partial dots over this thread's 16-col K-slice.
        // h-reads are wave-uniform addresses -> LDS broadcast.
        const float4* h4 = ((const float4*)hs) + q * 4;
        const float4 h0v = h4[0], h1v = h4[1], h2v = h4[2], h3v = h4[3];
        float a0 = 0.f, a1 = 0.f, a2 = 0.f;
        DOT4G(a0, a00, h0v); DOT4G(a0, a01, h1v); DOT4G(a0, a02, h2v); DOT4G(a0, a03, h3v);
        DOT4G(a1, a10, h0v); DOT4G(a1, a11, h1v); DOT4G(a1, a12, h2v); DOT4G(a1, a13, h3v);
        DOT4G(a2, a20, h0v); DOT4G(a2, a21, h1v); DOT4G(a2, a22, h2v); DOT4G(a2, a23, h3v);
        red[q][0][j] = a0; red[q][1][j] = a1; red[q][2][j] = a2;

        // prefetch next step's xg (overlaps barrier + phase B)
        float nxr = 0.f, nxz = 0.f, nxn = 0.f;
        if (tid < En) {
            const int tn = (t + 1 < len) ? t + 1 : t;
            nxr = xgb[tn*G3 + tid];
            nxz = xgb[tn*G3 + En + tid];
            nxn = xgb[tn*G3 + 2*En + tid];
        }
        __syncthreads();

        // phase B: reduce K-partials + gates (first 2 waves)
        if (tid < En) {
            float ar = red[0][0][tid], az = red[0][1][tid], an = red[0][2][tid];
            #pragma unroll
            for (int p = 1; p < 8; ++p) {
                ar += red[p][0][tid]; az += red[p][1][tid]; an += red[p][2][tid];
            }
            const float r = sigmoidf(xr + br + ar);
            const float z = sigmoidf(xz + bz + az);
            const float n = tanh_safe(xn + r * (bn + an));
            const float hnew = (1.0f - z) * n + z * hs[tid];
            hs[tid] = hnew;
            outb[t*En + tid] = hnew;
            xr = nxr; xz = nxz; xn = nxn;
        }
        __syncthreads();
    }

    if (tid < En) {
        for (int t = len; t < Tn; ++t) outb[t*En + tid] = 0.0f;
        out_h[(size_t)b * En + tid] = hs[tid];
    }
}

extern "C" void kernel_launch(void* const* d_in, const int* in_sizes, int n_in,
                              void* d_out, int out_size, void* d_ws, size_t ws_size,
                              hipStream_t stream) {
    const int*   item_ids     = (const int*)d_in[0];
    const int*   basket_sizes = (const int*)d_in[1];
    const int*   lengths      = (const int*)d_in[2];
    const float* emb          = (const float*)d_in[3];
    const float* W_ih         = (const float*)d_in[4];
    const float* W_hh         = (const float*)d_in[5];
    const float* b_ih         = (const float*)d_in[6];
    const float* b_hh         = (const float*)d_in[7];
    const float* h0           = (const float*)d_in[8];
    float* out = (float*)d_out;
    float* xg  = (float*)d_ws;   // 19.7 MB
    float* ub  = out;            // reuse out_dyn region; overwritten by gru later

    gather_kernel<<<(Bn * Tn) / 8, 256, 0, stream>>>(item_ids, basket_sizes, emb, ub);
    gemm_kernel<<<1200, 256, 0, stream>>>(ub, W_ih, b_ih, xg);
    gru_kernel<<<Bn, 1024, 0, stream>>>(
        lengths, W_hh, b_hh, h0, xg, out, out + (size_t)Bn * Tn * En);
}

// Round 12
// 177.149 us; speedup vs baseline: 1.0568x; 1.0568x over previous
//
#include <hip/hip_runtime.h>
#include <stdint.h>

#define Bn 256
#define Tn 50
#define Mn 20
#define En 128
#define G3 384
#define LDB 68    // padded LDS row stride for 64-float k-chunks

__device__ __forceinline__ float sigmoidf(float x) {
    return 1.0f / (1.0f + __expf(-x));
}
__device__ __forceinline__ float tanh_safe(float a) {
    float ax = fabsf(a);
    float e2 = __expf(-2.0f * ax);
    return copysignf((1.0f - e2) / (1.0f + e2), a);
}

// ---------------------------------------------------------------------------
// Kernel 1: basket-mean gather -> ub [B*T][128]  (stored in d_out region)
// ---------------------------------------------------------------------------
__global__ __launch_bounds__(256) void gather_kernel(
    const int*   __restrict__ item_ids,
    const int*   __restrict__ basket_sizes,
    const float* __restrict__ emb,
    float* __restrict__ ub)
{
    const int bt   = blockIdx.x * 8 + (threadIdx.x >> 5);
    const int lane = threadIdx.x & 31;
    const int* ids = item_ids + (size_t)bt * Mn;
    float ax = 0.f, ay = 0.f, az = 0.f, aw = 0.f;
    #pragma unroll
    for (int m = 0; m < Mn; ++m) {
        const float4 v = *(const float4*)(emb + (size_t)ids[m] * En + lane * 4);
        ax += v.x; ay += v.y; az += v.z; aw += v.w;
    }
    const float inv = 1.0f / (float)basket_sizes[bt];
    *(float4*)(ub + (size_t)bt * En + lane * 4) =
        make_float4(ax * inv, ay * inv, az * inv, aw * inv);
}

// ---------------------------------------------------------------------------
// Kernel 2: xg = ub @ W_ih^T + b_ih.
// 600 blocks = 100 M-tiles(128) x 6 N-chunks(64); 256 threads; 8x4 thread
// tile; K staged in two 64-chunks. 12 ds_read_b128 per 128 fma (was 8/64).
// LDS: A[128][68] + B[64][68] = 52.2 KB -> 3 blocks/CU.
// ---------------------------------------------------------------------------
__global__ __launch_bounds__(256) void gemm_kernel(
    const float* __restrict__ ub,
    const float* __restrict__ W_ih,
    const float* __restrict__ b_ih,
    float* __restrict__ xg)
{
    __shared__ float A[128][LDB];
    __shared__ float Bt[64][LDB];

    const int tid  = threadIdx.x;
    const int mt   = blockIdx.x / 6;
    const int nc   = blockIdx.x % 6;
    const int row0 = mt * 128;
    const int col0 = nc * 64;

    const int tx = tid & 15;   // N: cols tx + 16u, u<4
    const int ty = tid >> 4;   // M: rows ty + 16i, i<8

    float acc[8][4];
    #pragma unroll
    for (int i = 0; i < 8; ++i)
        #pragma unroll
        for (int u = 0; u < 4; ++u) acc[i][u] = 0.0f;

    #pragma unroll
    for (int kc = 0; kc < 2; ++kc) {
        const int k0 = kc * 64;
        // stage A: 2048 float4, 8 per thread
        #pragma unroll
        for (int c = 0; c < 8; ++c) {
            const int idx = tid + 256 * c;
            const int r = idx >> 4, seg = idx & 15;
            *(float4*)&A[r][seg * 4] =
                *(const float4*)(ub + (size_t)(row0 + r) * En + k0 + seg * 4);
        }
        // stage B: 1024 float4, 4 per thread
        #pragma unroll
        for (int c = 0; c < 4; ++c) {
            const int idx = tid + 256 * c;
            const int r = idx >> 4, seg = idx & 15;
            *(float4*)&Bt[r][seg * 4] =
                *(const float4*)(W_ih + (size_t)(col0 + r) * En + k0 + seg * 4);
        }
        __syncthreads();

        #pragma unroll 4
        for (int k4 = 0; k4 < 16; ++k4) {
            float4 bv[4];
            #pragma unroll
            for (int u = 0; u < 4; ++u)
                bv[u] = *(const float4*)&Bt[tx + 16*u][k4 * 4];
            #pragma unroll
            for (int i = 0; i < 8; ++i) {
                const float4 av = *(const float4*)&A[ty + 16*i][k4 * 4];
                #pragma unroll
                for (int u = 0; u < 4; ++u) {
                    acc[i][u] = fmaf(av.x, bv[u].x, acc[i][u]);
                    acc[i][u] = fmaf(av.y, bv[u].y, acc[i][u]);
                    acc[i][u] = fmaf(av.z, bv[u].z, acc[i][u]);
                    acc[i][u] = fmaf(av.w, bv[u].w, acc[i][u]);
                }
            }
        }
        __syncthreads();
    }

    float bias[4];
    #pragma unroll
    for (int u = 0; u < 4; ++u) bias[u] = b_ih[col0 + tx + 16*u];
    #pragma unroll
    for (int i = 0; i < 8; ++i) {
        const size_t rowoff = (size_t)(row0 + ty + 16*i) * G3;
        #pragma unroll
        for (int u = 0; u < 4; ++u)
            xg[rowoff + col0 + tx + 16*u] = acc[i][u] + bias[u];
    }
}

// ---------------------------------------------------------------------------
// Kernel 3: sequential GRU — EXACT R7 structure (proven correct + stable at
// 46.5 us across full harness incl. graph replay). 256 blocks x 1024 threads;
// thread (j,q) streams its 48 W_hh floats per step (compiler-scheduled).
// ---------------------------------------------------------------------------
__global__ __launch_bounds__(1024) void gru_kernel(
    const int*   __restrict__ lengths,
    const float* __restrict__ W_hh,
    const float* __restrict__ b_hh,
    const float* __restrict__ h0,
    const float* __restrict__ xg,
    float* __restrict__ out_dyn,
    float* __restrict__ out_h)
{
    __shared__ float hs[En];
    __shared__ float red[8][3][En];   // [q][gate][j], 12 KB

    const int tid = threadIdx.x;
    const int b   = blockIdx.x;
    const int j   = tid & 127;
    const int q   = tid >> 7;         // [0,8), wave-uniform

    // gate g row g*128+j, cols [q*16, q*16+16)
    float4 w0[4], w1[4], w2[4];
    {
        const float4* p0 = (const float4*)(W_hh + (size_t)(0*En + j) * En + q * 16);
        const float4* p1 = (const float4*)(W_hh + (size_t)(1*En + j) * En + q * 16);
        const float4* p2 = (const float4*)(W_hh + (size_t)(2*En + j) * En + q * 16);
        #pragma unroll
        for (int c = 0; c < 4; ++c) { w0[c] = p0[c]; w1[c] = p1[c]; w2[c] = p2[c]; }
    }

    const int len = lengths[b];
    const float* xgb = xg + (size_t)b * Tn * G3;
    float* outb = out_dyn + (size_t)b * Tn * En;

    float xr = 0.f, xz = 0.f, xn = 0.f, br = 0.f, bz = 0.f, bn = 0.f;
    if (tid < En) {
        hs[tid] = h0[(size_t)b * En + tid];
        br = b_hh[tid]; bz = b_hh[En + tid]; bn = b_hh[2*En + tid];
        xr = xgb[tid];  xz = xgb[En + tid]; xn = xgb[2*En + tid];
    }
    __syncthreads();

    for (int t = 0; t < len; ++t) {
        const float4* h4 = ((const float4*)hs) + q * 4;
        float a0 = 0.f, a1 = 0.f, a2 = 0.f;
        #pragma unroll
        for (int c = 0; c < 4; ++c) {
            const float4 hv = h4[c];
            a0 = fmaf(w0[c].x, hv.x, a0); a0 = fmaf(w0[c].y, hv.y, a0);
            a0 = fmaf(w0[c].z, hv.z, a0); a0 = fmaf(w0[c].w, hv.w, a0);
            a1 = fmaf(w1[c].x, hv.x, a1); a1 = fmaf(w1[c].y, hv.y, a1);
            a1 = fmaf(w1[c].z, hv.z, a1); a1 = fmaf(w1[c].w, hv.w, a1);
            a2 = fmaf(w2[c].x, hv.x, a2); a2 = fmaf(w2[c].y, hv.y, a2);
            a2 = fmaf(w2[c].z, hv.z, a2); a2 = fmaf(w2[c].w, hv.w, a2);
        }
        red[q][0][j] = a0; red[q][1][j] = a1; red[q][2][j] = a2;

        float nxr = 0.f, nxz = 0.f, nxn = 0.f;
        if (tid < En) {
            const int tn = (t + 1 < len) ? t + 1 : t;
            nxr = xgb[tn*G3 + tid];
            nxz = xgb[tn*G3 + En + tid];
            nxn = xgb[tn*G3 + 2*En + tid];
        }
        __syncthreads();

        if (tid < En) {
            float ar = red[0][0][tid], az = red[0][1][tid], an = red[0][2][tid];
            #pragma unroll
            for (int p = 1; p < 8; ++p) {
                ar += red[p][0][tid]; az += red[p][1][tid]; an += red[p][2][tid];
            }
            const float r = sigmoidf(xr + br + ar);
            const float z = sigmoidf(xz + bz + az);
            const float n = tanh_safe(xn + r * (bn + an));
            const float hnew = (1.0f - z) * n + z * hs[tid];
            hs[tid] = hnew;
            outb[t*En + tid] = hnew;
            xr = nxr; xz = nxz; xn = nxn;
        }
        __syncthreads();
    }

    if (tid < En) {
        for (int t = len; t < Tn; ++t) outb[t*En + tid] = 0.0f;
        out_h[(size_t)b * En + tid] = hs[tid];
    }
}

extern "C" void kernel_launch(void* const* d_in, const int* in_sizes, int n_in,
                              void* d_out, int out_size, void* d_ws, size_t ws_size,
                              hipStream_t stream) {
    const int*   item_ids     = (const int*)d_in[0];
    const int*   basket_sizes = (const int*)d_in[1];
    const int*   lengths      = (const int*)d_in[2];
    const float* emb          = (const float*)d_in[3];
    const float* W_ih         = (const float*)d_in[4];
    const float* W_hh         = (const float*)d_in[5];
    const float* b_ih         = (const float*)d_in[6];
    const float* b_hh         = (const float*)d_in[7];
    const float* h0           = (const float*)d_in[8];
    float* out = (float*)d_out;
    float* xg  = (float*)d_ws;   // 19.7 MB
    float* ub  = out;            // reuse out_dyn region; overwritten by gru later

    gather_kernel<<<(Bn * Tn) / 8, 256, 0, stream>>>(item_ids, basket_sizes, emb, ub);
    gemm_kernel<<<600, 256, 0, stream>>>(ub, W_ih, b_ih, xg);
    gru_kernel<<<Bn, 1024, 0, stream>>>(
        lengths, W_hh, b_hh, h0, xg, out, out + (size_t)Bn * Tn * En);
}